// Round 1
// baseline (282.793 us; speedup 1.0000x reference)
//
#include <hip/hip_runtime.h>
#include <hip/hip_bf16.h>

// Chunked simple-GLA forward, B=2 H=32 T=4096 K=V=128, BT=64.
// One fused kernel: grid = 64 (b,h) x 4 v-segments, 512 threads (8 waves).
// State slice [128 x 32] lives in MFMA accumulators for the whole T loop.

#define BT 64
#define KD 128
#define VD 128
#define VSG 32
#define NCHUNK 64
#define TLEN 4096
#define SCALE 0.08838834764831845f   // 128^-0.5

#define QSTR 136   // 128 + 8 bf16 pad (16B-aligned rows, 2-way max bank alias)
#define VSTR 40    // 32 + 8
#define SHSTR 72   // 64 + 8
#define SVSTR 136  // 128 + 8

typedef __bf16 bf16;
typedef __bf16 bf16x8 __attribute__((ext_vector_type(8)));
typedef __bf16 bf16x4 __attribute__((ext_vector_type(4)));
typedef float f32x4 __attribute__((ext_vector_type(4)));

// A/B fragment with contiguous K in LDS: elem j -> [row0+(l&15)][kk0+(l>>4)*8+j]
__device__ __forceinline__ bf16x8 frag_row(const bf16* p, int stride, int row0,
                                           int kk0, int lane) {
  int row = row0 + (lane & 15);
  int kk = kk0 + ((lane >> 4) << 3);
  return *(const bf16x8*)(p + row * stride + kk);
}

// Fragment whose K dim walks LDS rows (gather 8 scalars): elem j -> [rb0+(l>>4)*8+j][col]
__device__ __forceinline__ bf16x8 frag_col(const bf16* p, int stride, int rb0,
                                           int col, int lane) {
  int rb = rb0 + ((lane >> 4) << 3);
  bf16x8 f;
#pragma unroll
  for (int j = 0; j < 8; ++j) f[j] = p[(rb + j) * stride + col];
  return f;
}

__device__ __forceinline__ void st4(bf16* p, float a, float b, float c, float d) {
  bf16x4 t;
  t[0] = (bf16)a; t[1] = (bf16)b; t[2] = (bf16)c; t[3] = (bf16)d;
  *(bf16x4*)p = t;  // 8B LDS store
}

__global__ void __launch_bounds__(512, 2)
gla_fused(const float* __restrict__ qg, const float* __restrict__ kg,
          const float* __restrict__ vg, const float* __restrict__ gg,
          float* __restrict__ og)
{
  __shared__ __align__(16) bf16 q_s[BT][QSTR];
  __shared__ __align__(16) bf16 k_s[BT][QSTR];
  __shared__ __align__(16) bf16 v_s[BT][VSTR];
  __shared__ __align__(16) bf16 vw_s[BT][VSTR];
  __shared__ __align__(16) bf16 sh_s[BT][SHSTR];   // masked/gated s-hat (bf16)
  __shared__ __align__(16) bf16 svt_s[VSG][SVSTR]; // h_n slice, [vcol][kdim]
  __shared__ float gc_s[BT], w_s[BT], egc_s[BT];
  __shared__ float decay_s;

  const int tid = threadIdx.x;
  const int wave = tid >> 6;
  const int lane = tid & 63;
  // bid&63 = bh so the 4 v-segment blocks of one bh land on the same XCD
  const int bh = blockIdx.x & 63;
  const int vseg = blockIdx.x >> 6;

  const int jc = lane & 15;          // C col within tile
  const int r0 = ((lane >> 4) << 2); // C row group within tile

  const size_t qkbase = (size_t)bh * TLEN * KD;
  const size_t vbase = (size_t)bh * TLEN * VD + (size_t)vseg * VSG;
  const size_t gbase = (size_t)bh * TLEN;

  // s = q k^T tile assignment: wave -> Mtile (w&3), Ntiles {0,1} or {2,3}
  const int s_mt = wave & 3;
  const int s_nt0 = (wave < 4) ? 0 : 2;
  // output tile: wave -> Mtile (w&3), Ntile (w>>2)
  const int o_mt = wave & 3;
  const int o_nt = wave >> 2;

  // state slice: kdim rows [wave*16, +16), vcols [0,32): 2 accumulators
  f32x4 Sacc0 = {0.f, 0.f, 0.f, 0.f};
  f32x4 Sacc1 = {0.f, 0.f, 0.f, 0.f};

  const int vrow = tid >> 3;
  const int vcol = (tid & 7) << 2;

  for (int n = 0; n < NCHUNK; ++n) {
    __syncthreads();  // previous chunk's compute done -> LDS reusable

    // ---- gate scan (wave 0): inclusive cumsum of g over the 64-token chunk
    if (wave == 0) {
      float a = gg[gbase + n * BT + lane];
#pragma unroll
      for (int off = 1; off < 64; off <<= 1) {
        float t = __shfl_up(a, off);
        if (lane >= off) a += t;
      }
      float glast = __shfl(a, 63);
      gc_s[lane] = a;
      w_s[lane] = __expf(glast - a);        // per-token kv weight
      egc_s[lane] = __expf(a) * SCALE;      // o_inter row scale
      if (lane == 0) decay_s = __expf(glast);
    }

    // ---- stage q,k (full 128 cols) and v (this block's 32 cols), fp32->bf16
    float4 vreg;
    {
      const float4* q4 = (const float4*)(qg + qkbase + (size_t)n * (BT * KD));
      const float4* k4 = (const float4*)(kg + qkbase + (size_t)n * (BT * KD));
#pragma unroll
      for (int i = 0; i < 4; ++i) {
        int f4 = i * 512 + tid;
        int row = f4 >> 5;
        int col = (f4 & 31) << 2;
        float4 qv = q4[f4];
        float4 kv = k4[f4];
        st4(&q_s[row][col], qv.x, qv.y, qv.z, qv.w);
        st4(&k_s[row][col], kv.x, kv.y, kv.z, kv.w);
      }
      vreg = *(const float4*)(vg + vbase + (size_t)(n * BT + vrow) * VD + vcol);
      st4(&v_s[vrow][vcol], vreg.x, vreg.y, vreg.z, vreg.w);
    }

    __syncthreads();  // gates + q/k/v staged

    // ---- part 1: weighted v, export h_n to LDS, s = q k^T -> gated s-hat
    {
      float wv = w_s[vrow];
      st4(&vw_s[vrow][vcol], vreg.x * wv, vreg.y * wv, vreg.z * wv, vreg.w * wv);
    }
    {
      int kd0 = wave * 16 + r0;  // pre-update state = h_n (state entering chunk)
      st4(&svt_s[jc][kd0], Sacc0[0], Sacc0[1], Sacc0[2], Sacc0[3]);
      st4(&svt_s[16 + jc][kd0], Sacc1[0], Sacc1[1], Sacc1[2], Sacc1[3]);
    }
    {
      f32x4 sa0 = {0.f, 0.f, 0.f, 0.f}, sa1 = {0.f, 0.f, 0.f, 0.f};
#pragma unroll
      for (int ks = 0; ks < 4; ++ks) {
        bf16x8 a = frag_row(&q_s[0][0], QSTR, s_mt * 16, ks * 32, lane);
        bf16x8 b0 = frag_row(&k_s[0][0], QSTR, s_nt0 * 16, ks * 32, lane);
        bf16x8 b1 = frag_row(&k_s[0][0], QSTR, (s_nt0 + 1) * 16, ks * 32, lane);
        sa0 = __builtin_amdgcn_mfma_f32_16x16x32_bf16(a, b0, sa0, 0, 0, 0);
        sa1 = __builtin_amdgcn_mfma_f32_16x16x32_bf16(a, b1, sa1, 0, 0, 0);
      }
      // causal mask + gate exp(gc_i - gc_j) (<=1, no overflow) + scale
#pragma unroll
      for (int t = 0; t < 2; ++t) {
        f32x4 sv = t ? sa1 : sa0;
        int j = (s_nt0 + t) * 16 + jc;
        float gcj = gc_s[j];
#pragma unroll
        for (int r = 0; r < 4; ++r) {
          int i = s_mt * 16 + r0 + r;
          float val = (i >= j) ? sv[r] * __expf(gc_s[i] - gcj) * SCALE : 0.f;
          sh_s[i][j] = (bf16)val;
        }
      }
    }

    __syncthreads();  // s-hat, h_n, v*w visible to all waves

    // ---- part 2: o = (q @ h_n)*exp(gc)*scale + s-hat @ v ; state update
    {
      f32x4 oacc = {0.f, 0.f, 0.f, 0.f};
#pragma unroll
      for (int ks = 0; ks < 4; ++ks) {
        bf16x8 a = frag_row(&q_s[0][0], QSTR, o_mt * 16, ks * 32, lane);
        bf16x8 b = frag_row(&svt_s[0][0], SVSTR, o_nt * 16, ks * 32, lane);
        oacc = __builtin_amdgcn_mfma_f32_16x16x32_bf16(a, b, oacc, 0, 0, 0);
      }
#pragma unroll
      for (int r = 0; r < 4; ++r) oacc[r] *= egc_s[o_mt * 16 + r0 + r];
#pragma unroll
      for (int ks = 0; ks < 2; ++ks) {
        bf16x8 a = frag_row(&sh_s[0][0], SHSTR, o_mt * 16, ks * 32, lane);
        bf16x8 b = frag_col(&v_s[0][0], VSTR, ks * 32, o_nt * 16 + jc, lane);
        oacc = __builtin_amdgcn_mfma_f32_16x16x32_bf16(a, b, oacc, 0, 0, 0);
      }
      size_t ob = (size_t)bh * TLEN * VD + (size_t)vseg * VSG;
#pragma unroll
      for (int r = 0; r < 4; ++r) {
        int row = o_mt * 16 + r0 + r;
        og[ob + (size_t)(n * BT + row) * VD + o_nt * 16 + jc] = oacc[r];
      }
      // S = decay * S + k^T @ (v*w)   (accumulators stay resident)
      float dec = decay_s;
#pragma unroll
      for (int r = 0; r < 4; ++r) { Sacc0[r] *= dec; Sacc1[r] *= dec; }
#pragma unroll
      for (int ks = 0; ks < 2; ++ks) {
        bf16x8 a = frag_col(&k_s[0][0], QSTR, ks * 32, wave * 16 + jc, lane);
        bf16x8 b0 = frag_col(&vw_s[0][0], VSTR, ks * 32, jc, lane);
        bf16x8 b1 = frag_col(&vw_s[0][0], VSTR, ks * 32, 16 + jc, lane);
        Sacc0 = __builtin_amdgcn_mfma_f32_16x16x32_bf16(a, b0, Sacc0, 0, 0, 0);
        Sacc1 = __builtin_amdgcn_mfma_f32_16x16x32_bf16(a, b1, Sacc1, 0, 0, 0);
      }
    }
  }
}

extern "C" void kernel_launch(void* const* d_in, const int* in_sizes, int n_in,
                              void* d_out, int out_size, void* d_ws, size_t ws_size,
                              hipStream_t stream) {
  const float* q = (const float*)d_in[0];
  const float* k = (const float*)d_in[1];
  const float* v = (const float*)d_in[2];
  const float* g = (const float*)d_in[3];
  float* o = (float*)d_out;
  dim3 grid(256);   // 64 (b,h) x 4 v-segments
  dim3 block(512);  // 8 waves
  gla_fused<<<grid, block, 0, stream>>>(q, k, v, g, o);
}

// Round 2
// 206.814 us; speedup vs baseline: 1.3674x; 1.3674x over previous
//
#include <hip/hip_runtime.h>
#include <hip/hip_bf16.h>

// Chunked simple-GLA forward, B=2 H=32 T=4096 K=V=128, BT=64.
// grid = 64 (b,h) x 4 v-segments, 512 threads (8 waves).
// State slice S^T [32 vcols x 128 kdims] lives in MFMA accumulators.

#define BT 64
#define KD 128
#define VD 128
#define VSG 32
#define NCHUNK 64
#define TLEN 4096
#define SCALE 0.08838834764831845f   // 128^-0.5

#define QSTR 136   // q_s/k_s row stride (elems)
#define SHSTR 72   // s-hat row stride
#define SVSTR 136  // svt (h_n slice, [vc][kd]) row stride
#define VTSTR 72   // vT/vwT row stride (row = vcol, 64 t + pad)

typedef __bf16 bf16;
typedef __bf16 bf16x8 __attribute__((ext_vector_type(8)));
typedef __bf16 bf16x4 __attribute__((ext_vector_type(4)));
typedef float f32x4 __attribute__((ext_vector_type(4)));

// XOR-swizzled element offset into vT/vwT: conflict-free transposed stores,
// b128-aligned reads (XOR touches byte bits 4-6 only; bases are 16B-aligned).
__device__ __forceinline__ int vt_off(int vc, int t) {
  int byte = vc * (VTSTR * 2) + t * 2;
  byte ^= ((vc >> 2) & 7) << 4;
  return byte >> 1;
}

// A/B fragment, K contiguous in LDS: elem j -> [row0+(l&15)][kk0+(l>>4)*8+j]
__device__ __forceinline__ bf16x8 frag_row(const bf16* p, int stride, int row0,
                                           int kk0, int lane) {
  int row = row0 + (lane & 15);
  int kk = kk0 + ((lane >> 4) << 3);
  return *(const bf16x8*)(p + row * stride + kk);
}

// K walks LDS rows (8 scalar reads): elem j -> [rb0+(l>>4)*8+j][col]
__device__ __forceinline__ bf16x8 frag_col(const bf16* p, int stride, int rb0,
                                           int col, int lane) {
  int rb = rb0 + ((lane >> 4) << 3);
  bf16x8 f;
#pragma unroll
  for (int j = 0; j < 8; ++j) f[j] = p[(rb + j) * stride + col];
  return f;
}

__device__ __forceinline__ void st4(bf16* p, float a, float b, float c, float d) {
  bf16x4 t;
  t[0] = (bf16)a; t[1] = (bf16)b; t[2] = (bf16)c; t[3] = (bf16)d;
  *(bf16x4*)p = t;  // 8B LDS store
}

__global__ void __launch_bounds__(512, 2)
gla_fused(const float* __restrict__ qg, const float* __restrict__ kg,
          const float* __restrict__ vg, const float* __restrict__ gg,
          float* __restrict__ og)
{
  __shared__ __align__(16) bf16 q_s[BT][QSTR];
  __shared__ __align__(16) bf16 k_s[BT][QSTR];
  __shared__ __align__(16) bf16 vT_s[VSG * VTSTR];   // v^T  [vc][t], swizzled
  __shared__ __align__(16) bf16 vwT_s[VSG * VTSTR];  // (v*w)^T, swizzled
  __shared__ __align__(16) bf16 sh_s[BT][SHSTR];     // gated/masked s-hat
  __shared__ __align__(16) bf16 svt_s[VSG][SVSTR];   // h_n slice, [vc][kd]
  __shared__ float gc_s[BT], w_s[BT], egc_s[BT];
  __shared__ float decay_s;

  const int tid = threadIdx.x;
  const int wave = tid >> 6;
  const int lane = tid & 63;
  const int bh = blockIdx.x & 63;   // 4 vseg blocks of one bh share an XCD
  const int vseg = blockIdx.x >> 6;

  const int jc = lane & 15;
  const int g4 = lane >> 4;
  const int r0 = g4 << 2;

  const int mt = wave & 3;          // token 16-row tile (both s and o)
  const int nt = wave >> 2;         // o vcol tile
  const int nt0 = (wave < 4) ? 0 : 2;  // s-hat col tiles {nt0, nt0+1}

  const size_t qkbase = (size_t)bh * TLEN * KD;
  const size_t gbase = (size_t)bh * TLEN;
  const size_t vbase = (size_t)bh * TLEN * VD + (size_t)vseg * VSG;
  const int vrow = tid >> 3;
  const int vc0 = (tid & 7) << 2;

  // ---- prefetch chunk 0 into registers
  float4 qpf[4], kpf[4], vpf;
  {
    const float4* q4 = (const float4*)(qg + qkbase);
    const float4* k4 = (const float4*)(kg + qkbase);
#pragma unroll
    for (int i = 0; i < 4; ++i) { qpf[i] = q4[i * 512 + tid]; kpf[i] = k4[i * 512 + tid]; }
    vpf = *(const float4*)(vg + vbase + (size_t)vrow * VD + vc0);
  }

  // state S^T: acc0 = [vc 0..15][kd wave*16+jc], acc1 = [vc 16..31][...]
  f32x4 Sa = {0.f, 0.f, 0.f, 0.f};
  f32x4 Sb = {0.f, 0.f, 0.f, 0.f};

  for (int n = 0; n < NCHUNK; ++n) {
    __syncthreads();  // prev chunk's part2 done -> LDS reusable

    // ---- stage q,k (bf16 cvt) and vT from prefetch regs
#pragma unroll
    for (int i = 0; i < 4; ++i) {
      int f4 = i * 512 + tid;
      int row = f4 >> 5;
      int col = (f4 & 31) << 2;
      st4(&q_s[row][col], qpf[i].x, qpf[i].y, qpf[i].z, qpf[i].w);
      st4(&k_s[row][col], kpf[i].x, kpf[i].y, kpf[i].z, kpf[i].w);
    }
    float4 vcur = vpf;
    vT_s[vt_off(vc0 + 0, vrow)] = (bf16)vcur.x;
    vT_s[vt_off(vc0 + 1, vrow)] = (bf16)vcur.y;
    vT_s[vt_off(vc0 + 2, vrow)] = (bf16)vcur.z;
    vT_s[vt_off(vc0 + 3, vrow)] = (bf16)vcur.w;

    // ---- gate scan (wave 0)
    if (wave == 0) {
      float a = gg[gbase + n * BT + lane];
#pragma unroll
      for (int off = 1; off < 64; off <<= 1) {
        float t = __shfl_up(a, off);
        if (lane >= off) a += t;
      }
      float glast = __shfl(a, 63);
      gc_s[lane] = a;
      w_s[lane] = __expf(glast - a);
      egc_s[lane] = __expf(a) * SCALE;
      if (lane == 0) decay_s = __expf(glast);
    }

    __syncthreads();  // staged + gates visible

    // ---- issue prefetch for chunk n+1 (hides HBM latency under part1)
    if (n + 1 < NCHUNK) {
      const float4* q4 = (const float4*)(qg + qkbase + (size_t)(n + 1) * (BT * KD));
      const float4* k4 = (const float4*)(kg + qkbase + (size_t)(n + 1) * (BT * KD));
#pragma unroll
      for (int i = 0; i < 4; ++i) { qpf[i] = q4[i * 512 + tid]; kpf[i] = k4[i * 512 + tid]; }
      vpf = *(const float4*)(vg + vbase + (size_t)((n + 1) * BT + vrow) * VD + vc0);
    }

    // ---- part 1: vwT staging, h_n export, s = qk^T -> gated s-hat
    {
      float wv = w_s[vrow];
      vwT_s[vt_off(vc0 + 0, vrow)] = (bf16)(vcur.x * wv);
      vwT_s[vt_off(vc0 + 1, vrow)] = (bf16)(vcur.y * wv);
      vwT_s[vt_off(vc0 + 2, vrow)] = (bf16)(vcur.z * wv);
      vwT_s[vt_off(vc0 + 3, vrow)] = (bf16)(vcur.w * wv);
    }
#pragma unroll
    for (int r = 0; r < 4; ++r) {  // export pre-update state (h_n slice)
      svt_s[r0 + r][wave * 16 + jc] = (bf16)Sa[r];
      svt_s[16 + r0 + r][wave * 16 + jc] = (bf16)Sb[r];
    }

    bf16x8 af[4];  // q fragments, reused in part2
#pragma unroll
    for (int ks = 0; ks < 4; ++ks)
      af[ks] = frag_row(&q_s[0][0], QSTR, mt * 16, ks * 32, lane);

    {
      f32x4 sa0 = {0.f, 0.f, 0.f, 0.f}, sa1 = {0.f, 0.f, 0.f, 0.f};
#pragma unroll
      for (int ks = 0; ks < 4; ++ks) {
        bf16x8 b0 = frag_row(&k_s[0][0], QSTR, nt0 * 16, ks * 32, lane);
        bf16x8 b1 = frag_row(&k_s[0][0], QSTR, (nt0 + 1) * 16, ks * 32, lane);
        sa0 = __builtin_amdgcn_mfma_f32_16x16x32_bf16(af[ks], b0, sa0, 0, 0, 0);
        sa1 = __builtin_amdgcn_mfma_f32_16x16x32_bf16(af[ks], b1, sa1, 0, 0, 0);
      }
#pragma unroll
      for (int t = 0; t < 2; ++t) {
        f32x4 sv = t ? sa1 : sa0;
        int j = (nt0 + t) * 16 + jc;
        float gcj = gc_s[j];
#pragma unroll
        for (int r = 0; r < 4; ++r) {
          int i = mt * 16 + r0 + r;
          float val = (i >= j) ? sv[r] * __expf(gc_s[i] - gcj) * SCALE : 0.f;
          sh_s[i][j] = (bf16)val;
        }
      }
    }

    __syncthreads();  // s-hat, h_n, vwT visible

    // ---- part 2: o = (q@h_n)*egc + s-hat@v ; state update
    {
      f32x4 oacc = {0.f, 0.f, 0.f, 0.f};
#pragma unroll
      for (int ks = 0; ks < 4; ++ks) {
        bf16x8 b = frag_row(&svt_s[0][0], SVSTR, nt * 16, ks * 32, lane);
        oacc = __builtin_amdgcn_mfma_f32_16x16x32_bf16(af[ks], b, oacc, 0, 0, 0);
      }
#pragma unroll
      for (int r = 0; r < 4; ++r) oacc[r] *= egc_s[mt * 16 + r0 + r];
#pragma unroll
      for (int ks = 0; ks < 2; ++ks) {
        bf16x8 a = frag_row(&sh_s[0][0], SHSTR, mt * 16, ks * 32, lane);
        bf16x8 b = *(const bf16x8*)(vT_s + vt_off(nt * 16 + jc, ks * 32 + g4 * 8));
        oacc = __builtin_amdgcn_mfma_f32_16x16x32_bf16(a, b, oacc, 0, 0, 0);
      }
      size_t ob = (size_t)bh * TLEN * VD + (size_t)vseg * VSG;
#pragma unroll
      for (int r = 0; r < 4; ++r) {
        int row = mt * 16 + r0 + r;
        og[ob + (size_t)(n * BT + row) * VD + nt * 16 + jc] = oacc[r];
      }
      // S^T = dec * S^T + vw^T @ k
      float dec = decay_s;
#pragma unroll
      for (int r = 0; r < 4; ++r) { Sa[r] *= dec; Sb[r] *= dec; }
#pragma unroll
      for (int ks = 0; ks < 2; ++ks) {
        bf16x8 bk = frag_col(&k_s[0][0], QSTR, ks * 32, wave * 16 + jc, lane);
        bf16x8 a0 = *(const bf16x8*)(vwT_s + vt_off(jc, ks * 32 + g4 * 8));
        bf16x8 a1 = *(const bf16x8*)(vwT_s + vt_off(16 + jc, ks * 32 + g4 * 8));
        Sa = __builtin_amdgcn_mfma_f32_16x16x32_bf16(a0, bk, Sa, 0, 0, 0);
        Sb = __builtin_amdgcn_mfma_f32_16x16x32_bf16(a1, bk, Sb, 0, 0, 0);
      }
    }
  }
}

extern "C" void kernel_launch(void* const* d_in, const int* in_sizes, int n_in,
                              void* d_out, int out_size, void* d_ws, size_t ws_size,
                              hipStream_t stream) {
  const float* q = (const float*)d_in[0];
  const float* k = (const float*)d_in[1];
  const float* v = (const float*)d_in[2];
  const float* g = (const float*)d_in[3];
  float* o = (float*)d_out;
  dim3 grid(256);   // 64 (b,h) x 4 v-segments
  dim3 block(512);  // 8 waves
  gla_fused<<<grid, block, 0, stream>>>(q, k, v, g, o);
}